// Round 11
// baseline (244.447 us; speedup 1.0000x reference)
//
#include <hip/hip_runtime.h>

#define BB 4
#define TT 2048
#define CC 1024
#define HH 16
#define DD 64
#define WIN 256

typedef __attribute__((ext_vector_type(8))) short short8;
typedef __attribute__((ext_vector_type(4))) float floatx4;
typedef unsigned short u16;

typedef __attribute__((address_space(3))) void lds_void;
typedef const __attribute__((address_space(1))) void g_void;

__device__ __forceinline__ void gl_lds16(const u16* g, u16* l) {
    // async DMA global->LDS, 16B/lane; LDS dst = wave-uniform base + lane*16
    __builtin_amdgcn_global_load_lds((g_void*)g, (lds_void*)l, 16, 0, 0);
}

__device__ __forceinline__ float bf2f(u16 u) {
    union { unsigned int i; float f; } v; v.i = ((unsigned int)u) << 16; return v.f;
}
__device__ __forceinline__ u16 f2bf(float f) {
    union { float f; unsigned int i; } v; v.f = f;
    unsigned int x = v.i;
    x += ((x >> 16) & 1u) + 0x7FFFu;   // round-to-nearest-even
    return (u16)(x >> 16);
}

// ---------------- fp32 -> bf16 conversion (all three arrays, one launch) -----
__global__ void cvt_all(const float* __restrict__ x, const float* __restrict__ qw,
                        const float* __restrict__ pw,
                        u16* __restrict__ xb, u16* __restrict__ wb, u16* __restrict__ pwb) {
    int bid = blockIdx.x;
    const float* src; u16* dst; int off;
    if (bid < 4096)      { src = x;  dst = xb;  off = bid; }
    else if (bid < 5632) { src = qw; dst = wb;  off = bid - 4096; }
    else                 { src = pw; dst = pwb; off = bid - 5632; }
    int i = (off * 256 + (int)threadIdx.x) * 8;
    float4 a = *(const float4*)(src + i);
    float4 b = *(const float4*)(src + i + 4);
    u16 o[8] = { f2bf(a.x), f2bf(a.y), f2bf(a.z), f2bf(a.w),
                 f2bf(b.x), f2bf(b.y), f2bf(b.z), f2bf(b.w) };
    *(uint4*)(dst + i) = *(const uint4*)o;
}

#define VM2()  asm volatile("s_waitcnt vmcnt(2)" ::: "memory")
#define BARX() do { asm volatile("" ::: "memory");                           \
        __builtin_amdgcn_s_barrier();                                        \
        asm volatile("" ::: "memory"); } while (0)

// ============================================================================
// 128 x (64*NR) bf16 GEMM tile, BK=64, barrier-light double-buffer ledger,
// sized for 2 blocks/CU (co-resident block fills the barrier/vmcnt envelope).
//   512 threads = 8 waves (2M x 4N); per-wave output 64 x (NR*16); acc 4xNR.
//   LDS (qkv NR=3): lA 2x16KB + lB 2x24KB = 80KB -> exactly 2 blocks/CU.
//   Segment (16r x 32c, 1KB): chunk (row,c) at (row&15)*64B + (c^((row>>1)&3))*16B
//   -> conflict-free ds_read_b128 (measured 0 across all predecessors); DMA
//   staging inverts the swizzle via precomputed per-thread source pointers.
//   Per K-tile t (buf p=t&1), 2 barriers + 1 counted vmcnt:
//     stgA(p^1,t+1)[2]; vmcnt(2); BAR; lda(p,0); ldb(p,0); mm;
//     stgB(p^1,t+1)[NR];           lda(p,1); ldb(p,1); mm; BAR;
//   At VM2: in-flight = [A(t) rem, B(t)[NR], A(t+1)[2]]; keeping the 2 newest
//   (= A(t+1)) completes tile t exactly. Tail clamps t+1 -> 15 (dead restage).
//   WAR safe: buf p^1 writes issue only after tile t-1's end-barrier.
// ============================================================================
template<int NR>
__device__ __forceinline__ void gemm_core(
    const u16* __restrict__ Amat, const u16* __restrict__ Bw,
    int bM, int bN, u16* lA, u16* lB, floatx4 (&acc)[4][NR])
{
    const int K = CC;
    const int tid = threadIdx.x;
    const int wave = tid >> 6, lane = tid & 63;
    const int wm = wave >> 2, wn = wave & 3;        // 2M x 4N
    const int quad = lane >> 4, l15 = lane & 15;

    // staging source pointers (inverse of the LDS segment swizzle)
    const u16* gA[2]; int dA[2];
#pragma unroll
    for (int j = 0; j < 2; ++j) {
        int off = j * 8192 + tid * 16;              // byte offset in 16KB A tile
        int kh  = off >> 13;                        // half = 128r x 32c = 8KB
        int o2  = off & 8191;
        int row = (o2 >> 10) * 16 + ((o2 & 1023) >> 6);
        int c   = ((o2 >> 4) & 3) ^ ((row >> 1) & 3);
        gA[j] = Amat + (size_t)(bM + row) * K + kh * 32 + c * 8;
        dA[j] = off >> 1;                           // u16 index
    }
    const u16* gB[NR]; int dB[NR];
#pragma unroll
    for (int j = 0; j < NR; ++j) {
        int off = j * 8192 + tid * 16;              // byte offset in NR*8KB B tile
        int kh  = (off >= NR * 4096) ? 1 : 0;       // half = NR*64 r x 32c
        int o2  = off - kh * NR * 4096;
        int row = (o2 >> 10) * 16 + ((o2 & 1023) >> 6);
        int c   = ((o2 >> 4) & 3) ^ ((row >> 1) & 3);
        gB[j] = Bw + (size_t)(bN + row) * K + kh * 32 + c * 8;
        dB[j] = off >> 1;
    }

    const int rdoff = l15 * 32 + ((quad ^ ((l15 >> 1) & 3)) * 8);

    short8 af[4], bf[NR];

    auto stgA = [&](int buf, int t) {
#pragma unroll
        for (int j = 0; j < 2; ++j)
            gl_lds16(gA[j] + t * 64, lA + buf * 8192 + dA[j]);
    };
    auto stgB = [&](int buf, int t) {
#pragma unroll
        for (int j = 0; j < NR; ++j)
            gl_lds16(gB[j] + t * 64, lB + buf * (NR * 4096) + dB[j]);
    };
    auto lda = [&](int buf, int kh) {
#pragma unroll
        for (int i = 0; i < 4; ++i)
            af[i] = *(const short8*)&lA[buf * 8192 + kh * 4096 + (wm * 4 + i) * 512 + rdoff];
    };
    auto ldb = [&](int buf, int kh) {
#pragma unroll
        for (int j = 0; j < NR; ++j)
            bf[j] = *(const short8*)&lB[buf * (NR * 4096) + kh * (NR * 2048) + (wn * NR + j) * 512 + rdoff];
    };
    auto mm = [&]() {
        __builtin_amdgcn_s_setprio(1);
#pragma unroll
        for (int i = 0; i < 4; ++i)
#pragma unroll
            for (int j = 0; j < NR; ++j)
                acc[i][j] = __builtin_amdgcn_mfma_f32_16x16x32_bf16(af[i], bf[j], acc[i][j], 0, 0, 0);
        __builtin_amdgcn_s_setprio(0);
    };

    // prologue: tile 0 into buf 0
    stgA(0, 0); stgB(0, 0);

    for (int ii = 0; ii < 8; ++ii) {
        const int t1 = 2 * ii + 1;
        const int t2 = (ii < 7) ? 2 * ii + 2 : 15;   // tail clamp (dead restage)
        // tile even (buf 0)
        stgA(1, t1); VM2(); BARX();
        lda(0, 0); ldb(0, 0); mm();
        stgB(1, t1);
        lda(0, 1); ldb(0, 1); mm();
        BARX();
        // tile odd (buf 1)
        stgA(0, t2); VM2(); BARX();
        lda(1, 0); ldb(1, 0); mm();
        stgB(0, t2);
        lda(1, 1); ldb(1, 1); mm();
        BARX();
    }
}

// ---- QKV: C = xb @ qkv_w^T (+bias), scatter into Q/K/V [B*H, T, D] bf16 ----
// Tile 128x192 (NR=3), 80KB LDS -> 2 blocks/CU; grid 1024 = 2 rounds of 512.
__global__ __launch_bounds__(512, 4) void gemm_qkv(
    const u16* __restrict__ Amat, const u16* __restrict__ Bw,
    const float* __restrict__ bias,
    u16* __restrict__ Qb, u16* __restrict__ Kb, u16* __restrict__ Vb)
{
    __shared__ u16 lA[2 * 8192];    // 32 KB
    __shared__ u16 lB[2 * 12288];   // 48 KB
    // XCD x owns m-tiles 8x..8x+7 (A slice 1MB, L2-resident), all 16 n-tiles.
    const int raw = blockIdx.x;
    const int xcd = raw & 7;
    const int l   = raw >> 3;               // 0..127
    const int bM  = (xcd * 8 + (l & 7)) * 128;
    const int bN  = (l >> 3) * 192;         // n-tile 0..15

    floatx4 acc[4][3] = {};
    gemm_core<3>(Amat, Bw, bM, bN, lA, lB, acc);

    const int tid = threadIdx.x;
    const int wave = tid >> 6, lane = tid & 63;
    const int wm = wave >> 2, wn = wave & 3;
    const int quad = lane >> 4, l15 = lane & 15;

    // epilogue: +bias, bf16, QKV scatter
#pragma unroll
    for (int mf = 0; mf < 4; ++mf)
#pragma unroll
        for (int nf = 0; nf < 3; ++nf) {
            int col = bN + wn * 48 + nf * 16 + l15;          // 0..3071
            float bv = bias[col];
            int which = col >> 10, rem = col & 1023;
            int h = rem >> 6, d = rem & 63;
            u16* dst = which == 0 ? Qb : (which == 1 ? Kb : Vb);
#pragma unroll
            for (int rg = 0; rg < 4; ++rg) {
                int row = bM + wm * 64 + mf * 16 + quad * 4 + rg;  // 0..8191
                int b = row >> 11, t = row & 2047;
                float v = acc[mf][nf][rg] + bv;
                dst[(((size_t)(b * HH + h)) * TT + t) * DD + d] = f2bf(v);
            }
        }
}

// ---- proj: Out = Yb @ proj_w^T + bias (fp32 out) ----
// R11: BK=32 single-chunk pipeline; LDS 32KB -> 4 blocks/CU (thread-limited).
// Per K-tile t (buf p=t&1): stg(p^1,t+1)[A 1 load + B 1 load]; vmcnt(2)
// (keeps only the 2 newest = tile t+1's loads -> tile t landed); BAR;
// ld(p); 8 MFMA; BAR. Same 0-conflict segment geometry; tail restages t=31.
__global__ __launch_bounds__(512, 8) void gemm_proj(
    const u16* __restrict__ Amat, const u16* __restrict__ Bw,
    const float* __restrict__ bias, float* __restrict__ Out)
{
    const int K = CC;
    __shared__ u16 lA[2 * 4096];    // 16 KB (128r x 32c per buf)
    __shared__ u16 lB[2 * 4096];    // 16 KB
    const int raw = blockIdx.x;
    const int xcd = raw & 7;
    const int l   = raw >> 3;               // 0..63
    const int bM  = (xcd * 8 + (l & 7)) * 128;
    const int bN  = (l >> 3) * 128;         // n-tile 0..7

    const int tid = threadIdx.x;
    const int wave = tid >> 6, lane = tid & 63;
    const int wm = wave >> 2, wn = wave & 3;        // 2M x 4N
    const int quad = lane >> 4, l15 = lane & 15;

    // staging source pointers (inverse of the LDS segment swizzle); 1 chunk each
    const int off = tid * 16;                       // byte offset in 8KB chunk
    const int row = (off >> 10) * 16 + ((off & 1023) >> 6);
    const int c   = ((off >> 4) & 3) ^ ((row >> 1) & 3);
    const u16* gA0 = Amat + (size_t)(bM + row) * K + c * 8;
    const u16* gB0 = Bw + (size_t)(bN + row) * K + c * 8;
    const int d0 = off >> 1;                        // u16 index

    const int rdoff = l15 * 32 + ((quad ^ ((l15 >> 1) & 3)) * 8);

    floatx4 acc[4][2] = {};
    short8 af[4], bf[2];

    auto stg = [&](int buf, int t) {
        gl_lds16(gA0 + t * 32, lA + buf * 4096 + d0);
        gl_lds16(gB0 + t * 32, lB + buf * 4096 + d0);
    };
    auto ld = [&](int buf) {
#pragma unroll
        for (int i = 0; i < 4; ++i)
            af[i] = *(const short8*)&lA[buf * 4096 + (wm * 4 + i) * 512 + rdoff];
#pragma unroll
        for (int j = 0; j < 2; ++j)
            bf[j] = *(const short8*)&lB[buf * 4096 + (wn * 2 + j) * 512 + rdoff];
    };
    auto mm = [&]() {
        __builtin_amdgcn_s_setprio(1);
#pragma unroll
        for (int i = 0; i < 4; ++i)
#pragma unroll
            for (int j = 0; j < 2; ++j)
                acc[i][j] = __builtin_amdgcn_mfma_f32_16x16x32_bf16(af[i], bf[j], acc[i][j], 0, 0, 0);
        __builtin_amdgcn_s_setprio(0);
    };

    stg(0, 0);
    for (int ii = 0; ii < 16; ++ii) {
        const int t1 = 2 * ii + 1;
        const int t2 = (ii < 15) ? 2 * ii + 2 : 31;  // tail clamp (dead restage)
        // tile even (buf 0)
        stg(1, t1); VM2(); BARX();
        ld(0); mm();
        BARX();
        // tile odd (buf 1)
        stg(0, t2); VM2(); BARX();
        ld(1); mm();
        BARX();
    }

    // epilogue: +bias, fp32 out
#pragma unroll
    for (int mf = 0; mf < 4; ++mf)
#pragma unroll
        for (int nf = 0; nf < 2; ++nf) {
            int col = bN + wn * 32 + nf * 16 + l15;
            float bv = bias[col];
#pragma unroll
            for (int rg = 0; rg < 4; ++rg) {
                int rw = bM + wm * 64 + mf * 16 + quad * 4 + rg;
                Out[(size_t)rw * CC + col] = acc[mf][nf][rg] + bv;
            }
        }
}

// ---------------- flash attention, MFMA (bf16 in, fp32 acc) ------------------
// Q/K/V: [B*H, T, D] bf16.  Y: [B, T, C] bf16 (transposed for proj GEMM)
// Block: 256 threads = 4 waves; 64 queries/block (16/wave); key chunks of 64.
// Grid (bh, qtile): linear id = bh + 64*qtile -> all q-tiles of a head hit the
// SAME XCD (id%8 = bh%8) -> K/V chunks L2-resident across their ~5 consumer
// q-tiles. (Byte-exact revert to the R8 structure; the R9/R10 mask-skip and
// skip-rescale branches measured +10.7us and are removed.)
__global__ __launch_bounds__(256) void attn_mfma(
    const u16* __restrict__ Qb, const u16* __restrict__ Kb, const u16* __restrict__ Vb,
    u16* __restrict__ Y)
{
    __shared__ u16 Ks[64][72];        // K chunk, [j][d], +8 pad
    __shared__ u16 Vt[64][72];        // V chunk transposed [d][j], XOR-swizzled j-blocks
    __shared__ u16 Ps[4][16][72];     // per-wave P round-trip buffer [q][j]

    const int tid = threadIdx.x;
    const int wave = tid >> 6, lane = tid & 63;
    const int quad = lane >> 4, l15 = lane & 15;
    const int q0 = blockIdx.y * 64;
    const int bh = blockIdx.x;
    const int b = bh >> 4, h = bh & 15;
    const u16* Qp = Qb + (size_t)bh * TT * DD;
    const u16* Kp = Kb + (size_t)bh * TT * DD;
    const u16* Vp = Vb + (size_t)bh * TT * DD;
    const int qw = q0 + wave * 16;    // this wave's first query

    // Q A-fragments: m=l15 (query), k=quad*8+j (d), 2 k-steps
    short8 qf[2];
    qf[0] = *(const short8*)&Qp[(size_t)(qw + l15) * DD + quad * 8];
    qf[1] = *(const short8*)&Qp[(size_t)(qw + l15) * DD + 32 + quad * 8];

    float m_i[4] = { -1e30f, -1e30f, -1e30f, -1e30f };
    float l_i[4] = { 0.f, 0.f, 0.f, 0.f };
    floatx4 Oacc[4] = {};             // [dtile]; C layout: row=quad*4+reg, col(d)=dt*16+l15

    const int kb = (q0 >= WIN) ? (q0 - WIN) : 0;
    for (int j0 = kb; j0 < q0 + 64; j0 += 64) {
        __syncthreads();
        // stage K chunk [j][d], vectorized
#pragma unroll
        for (int it = 0; it < 2; ++it) {
            int slot = tid + it * 256;
            int j = slot >> 3, c8 = (slot & 7) << 3;
            *(uint4*)&Ks[j][c8] = *(const uint4*)&Kp[(size_t)(j0 + j) * DD + c8];
        }
        // stage V transposed [d][j], swizzle j-block by d>>3 (conflict-free writes)
#pragma unroll
        for (int it = 0; it < 2; ++it) {
            int slot = tid + it * 256;
            int j = slot >> 3, d0 = (slot & 7) << 3;
            uint4 raw = *(const uint4*)&Vp[(size_t)(j0 + j) * DD + d0];
            const u16* u = (const u16*)&raw;
#pragma unroll
            for (int i = 0; i < 8; ++i) {
                int d = d0 + i;
                int col = (((j >> 3) ^ (d >> 3)) << 3) + (j & 7);
                Vt[d][col] = u[i];
            }
        }
        __syncthreads();

        // ---- S = Q K^T (scaled), 4 n-tiles of 16 keys ----
        floatx4 Sacc[4] = {};
        __builtin_amdgcn_s_setprio(1);
#pragma unroll
        for (int nt = 0; nt < 4; ++nt) {
            short8 kf0 = *(const short8*)&Ks[nt * 16 + l15][quad * 8];
            short8 kf1 = *(const short8*)&Ks[nt * 16 + l15][32 + quad * 8];
            Sacc[nt] = __builtin_amdgcn_mfma_f32_16x16x32_bf16(qf[0], kf0, Sacc[nt], 0, 0, 0);
            Sacc[nt] = __builtin_amdgcn_mfma_f32_16x16x32_bf16(qf[1], kf1, Sacc[nt], 0, 0, 0);
        }
        __builtin_amdgcn_s_setprio(0);

        // ---- mask + scale + chunk row-max ----
        float mc[4] = { -1e30f, -1e30f, -1e30f, -1e30f };
#pragma unroll
        for (int nt = 0; nt < 4; ++nt)
#pragma unroll
            for (int r = 0; r < 4; ++r) {
                int q = qw + quad * 4 + r;
                int j = j0 + nt * 16 + l15;
                float s = (j <= q && (q - j) < WIN) ? Sacc[nt][r] * 0.125f : -1e30f;
                Sacc[nt][r] = s;
                mc[r] = fmaxf(mc[r], s);
            }
#pragma unroll
        for (int m = 1; m < 16; m <<= 1)
#pragma unroll
            for (int r = 0; r < 4; ++r) mc[r] = fmaxf(mc[r], __shfl_xor(mc[r], m, 64));

        // ---- online softmax update ----
        float alpha[4];
#pragma unroll
        for (int r = 0; r < 4; ++r) {
            float mn = fmaxf(m_i[r], mc[r]);
            alpha[r] = __expf(m_i[r] - mn);
            m_i[r] = mn;
        }
        float rs[4] = { 0.f, 0.f, 0.f, 0.f };
#pragma unroll
        for (int nt = 0; nt < 4; ++nt)
#pragma unroll
            for (int r = 0; r < 4; ++r) {
                float s = Sacc[nt][r];
                float p = (s > -1e29f) ? __expf(s - m_i[r]) : 0.f;
                Sacc[nt][r] = p;
                rs[r] += p;
            }
#pragma unroll
        for (int m = 1; m < 16; m <<= 1)
#pragma unroll
            for (int r = 0; r < 4; ++r) rs[r] += __shfl_xor(rs[r], m, 64);
#pragma unroll
        for (int r = 0; r < 4; ++r) l_i[r] = l_i[r] * alpha[r] + rs[r];
#pragma unroll
        for (int dt = 0; dt < 4; ++dt)
#pragma unroll
            for (int r = 0; r < 4; ++r) Oacc[dt][r] *= alpha[r];

        // ---- P (C layout) -> LDS -> A layout; per-wave, no barrier needed ----
#pragma unroll
        for (int nt = 0; nt < 4; ++nt)
#pragma unroll
            for (int r = 0; r < 4; ++r)
                Ps[wave][quad * 4 + r][nt * 16 + l15] = f2bf(Sacc[nt][r]);

        // ---- O += P V ----
        __builtin_amdgcn_s_setprio(1);
#pragma unroll
        for (int ks = 0; ks < 2; ++ks) {
            short8 pf = *(const short8*)&Ps[wave][l15][ks * 32 + quad * 8];
#pragma unroll
            for (int dt = 0; dt < 4; ++dt) {
                int d = dt * 16 + l15;
                int col = (((ks * 4 + quad) ^ (d >> 3)) << 3);
                short8 vf = *(const short8*)&Vt[d][col];
                Oacc[dt] = __builtin_amdgcn_mfma_f32_16x16x32_bf16(pf, vf, Oacc[dt], 0, 0, 0);
            }
        }
        __builtin_amdgcn_s_setprio(0);
    }

    // ---- epilogue: O / l, write Y[b,t,h*64+d] ----
    float inv[4];
#pragma unroll
    for (int r = 0; r < 4; ++r) inv[r] = 1.f / l_i[r];
#pragma unroll
    for (int dt = 0; dt < 4; ++dt)
#pragma unroll
        for (int r = 0; r < 4; ++r) {
            int t = qw + quad * 4 + r;
            int d = dt * 16 + l15;
            Y[((size_t)b * TT + t) * CC + h * DD + d] = f2bf(Oacc[dt][r] * inv[r]);
        }
}

// ---------------- launch ----------------
extern "C" void kernel_launch(void* const* d_in, const int* in_sizes, int n_in,
                              void* d_out, int out_size, void* d_ws, size_t ws_size,
                              hipStream_t stream) {
    const float* x      = (const float*)d_in[0];
    // d_in[1] = attn_mask (bool) — mask structure is analytic, unused
    const float* qkv_w  = (const float*)d_in[2];
    const float* qkv_b  = (const float*)d_in[3];
    const float* proj_w = (const float*)d_in[4];
    const float* proj_b = (const float*)d_in[5];
    float* out = (float*)d_out;

    u16* xb  = (u16*)d_ws;                         // 8192*1024
    u16* wb  = xb  + (size_t)8192 * 1024;          // 3072*1024
    u16* pwb = wb  + (size_t)3072 * 1024;          // 1024*1024
    u16* Qb  = pwb + (size_t)1024 * 1024;          // 64*2048*64
    u16* Kb  = Qb  + (size_t)64 * 2048 * 64;
    u16* Vb  = Kb  + (size_t)64 * 2048 * 64;
    u16* Yb  = Vb  + (size_t)64 * 2048 * 64;       // 8192*1024

    cvt_all<<<6144, 256, 0, stream>>>(x, qkv_w, proj_w, xb, wb, pwb);
    gemm_qkv<<<1024, 512, 0, stream>>>(xb, wb, qkv_b, Qb, Kb, Vb);
    attn_mfma<<<dim3(BB * HH, TT / 64), 256, 0, stream>>>(Qb, Kb, Vb, Yb);
    gemm_proj<<<512, 512, 0, stream>>>(Yb, pwb, proj_b, out);
}

// Round 12
// 219.921 us; speedup vs baseline: 1.1115x; 1.1115x over previous
//
#include <hip/hip_runtime.h>

#define BB 4
#define TT 2048
#define CC 1024
#define HH 16
#define DD 64
#define WIN 256

typedef __attribute__((ext_vector_type(8))) short short8;
typedef __attribute__((ext_vector_type(4))) float floatx4;
typedef unsigned short u16;

typedef __attribute__((address_space(3))) void lds_void;
typedef const __attribute__((address_space(1))) void g_void;

__device__ __forceinline__ void gl_lds16(const u16* g, u16* l) {
    // async DMA global->LDS, 16B/lane; LDS dst = wave-uniform base + lane*16
    __builtin_amdgcn_global_load_lds((g_void*)g, (lds_void*)l, 16, 0, 0);
}

__device__ __forceinline__ float bf2f(u16 u) {
    union { unsigned int i; float f; } v; v.i = ((unsigned int)u) << 16; return v.f;
}
__device__ __forceinline__ u16 f2bf(float f) {
    union { float f; unsigned int i; } v; v.f = f;
    unsigned int x = v.i;
    x += ((x >> 16) & 1u) + 0x7FFFu;   // round-to-nearest-even
    return (u16)(x >> 16);
}

// ---------------- fp32 -> bf16 conversion (all three arrays, one launch) -----
__global__ void cvt_all(const float* __restrict__ x, const float* __restrict__ qw,
                        const float* __restrict__ pw,
                        u16* __restrict__ xb, u16* __restrict__ wb, u16* __restrict__ pwb) {
    int bid = blockIdx.x;
    const float* src; u16* dst; int off;
    if (bid < 4096)      { src = x;  dst = xb;  off = bid; }
    else if (bid < 5632) { src = qw; dst = wb;  off = bid - 4096; }
    else                 { src = pw; dst = pwb; off = bid - 5632; }
    int i = (off * 256 + (int)threadIdx.x) * 8;
    float4 a = *(const float4*)(src + i);
    float4 b = *(const float4*)(src + i + 4);
    u16 o[8] = { f2bf(a.x), f2bf(a.y), f2bf(a.z), f2bf(a.w),
                 f2bf(b.x), f2bf(b.y), f2bf(b.z), f2bf(b.w) };
    *(uint4*)(dst + i) = *(const uint4*)o;
}

#define VM2()  asm volatile("s_waitcnt vmcnt(2)" ::: "memory")
#define BARX() do { asm volatile("" ::: "memory");                           \
        __builtin_amdgcn_s_barrier();                                        \
        asm volatile("" ::: "memory"); } while (0)

// ============================================================================
// 128 x (64*NR) bf16 GEMM tile, BK=64, barrier-light double-buffer ledger,
// sized for 2 blocks/CU (co-resident block fills the barrier/vmcnt envelope).
//   512 threads = 8 waves (2M x 4N); per-wave output 64 x (NR*16); acc 4xNR.
//   LDS (qkv NR=3): lA 2x16KB + lB 2x24KB = 80KB -> exactly 2 blocks/CU.
//   Segment (16r x 32c, 1KB): chunk (row,c) at (row&15)*64B + (c^((row>>1)&3))*16B
//   -> conflict-free ds_read_b128 (measured 0 across all predecessors); DMA
//   staging inverts the swizzle via precomputed per-thread source pointers.
//   Per K-tile t (buf p=t&1), 2 barriers + 1 counted vmcnt:
//     stgA(p^1,t+1)[2]; vmcnt(2); BAR; lda(p,0); ldb(p,0); mm;
//     stgB(p^1,t+1)[NR];           lda(p,1); ldb(p,1); mm; BAR;
//   At VM2: in-flight = [A(t) rem, B(t)[NR], A(t+1)[2]]; keeping the 2 newest
//   (= A(t+1)) completes tile t exactly. Tail clamps t+1 -> 15 (dead restage).
//   WAR safe: buf p^1 writes issue only after tile t-1's end-barrier.
//   Session lessons (measured): BK=32 halves MFMA/barrier -> +25us on proj
//   (R11); 1 block/CU starves the envelope (R5); attn-side wave-uniform
//   branch "optimizations" cost +11us (R9/R10). This config is the minimum
//   of everything measured across 11 rounds.
// ============================================================================
template<int NR>
__device__ __forceinline__ void gemm_core(
    const u16* __restrict__ Amat, const u16* __restrict__ Bw,
    int bM, int bN, u16* lA, u16* lB, floatx4 (&acc)[4][NR])
{
    const int K = CC;
    const int tid = threadIdx.x;
    const int wave = tid >> 6, lane = tid & 63;
    const int wm = wave >> 2, wn = wave & 3;        // 2M x 4N
    const int quad = lane >> 4, l15 = lane & 15;

    // staging source pointers (inverse of the LDS segment swizzle)
    const u16* gA[2]; int dA[2];
#pragma unroll
    for (int j = 0; j < 2; ++j) {
        int off = j * 8192 + tid * 16;              // byte offset in 16KB A tile
        int kh  = off >> 13;                        // half = 128r x 32c = 8KB
        int o2  = off & 8191;
        int row = (o2 >> 10) * 16 + ((o2 & 1023) >> 6);
        int c   = ((o2 >> 4) & 3) ^ ((row >> 1) & 3);
        gA[j] = Amat + (size_t)(bM + row) * K + kh * 32 + c * 8;
        dA[j] = off >> 1;                           // u16 index
    }
    const u16* gB[NR]; int dB[NR];
#pragma unroll
    for (int j = 0; j < NR; ++j) {
        int off = j * 8192 + tid * 16;              // byte offset in NR*8KB B tile
        int kh  = (off >= NR * 4096) ? 1 : 0;       // half = NR*64 r x 32c
        int o2  = off - kh * NR * 4096;
        int row = (o2 >> 10) * 16 + ((o2 & 1023) >> 6);
        int c   = ((o2 >> 4) & 3) ^ ((row >> 1) & 3);
        gB[j] = Bw + (size_t)(bN + row) * K + kh * 32 + c * 8;
        dB[j] = off >> 1;
    }

    const int rdoff = l15 * 32 + ((quad ^ ((l15 >> 1) & 3)) * 8);

    short8 af[4], bf[NR];

    auto stgA = [&](int buf, int t) {
#pragma unroll
        for (int j = 0; j < 2; ++j)
            gl_lds16(gA[j] + t * 64, lA + buf * 8192 + dA[j]);
    };
    auto stgB = [&](int buf, int t) {
#pragma unroll
        for (int j = 0; j < NR; ++j)
            gl_lds16(gB[j] + t * 64, lB + buf * (NR * 4096) + dB[j]);
    };
    auto lda = [&](int buf, int kh) {
#pragma unroll
        for (int i = 0; i < 4; ++i)
            af[i] = *(const short8*)&lA[buf * 8192 + kh * 4096 + (wm * 4 + i) * 512 + rdoff];
    };
    auto ldb = [&](int buf, int kh) {
#pragma unroll
        for (int j = 0; j < NR; ++j)
            bf[j] = *(const short8*)&lB[buf * (NR * 4096) + kh * (NR * 2048) + (wn * NR + j) * 512 + rdoff];
    };
    auto mm = [&]() {
        __builtin_amdgcn_s_setprio(1);
#pragma unroll
        for (int i = 0; i < 4; ++i)
#pragma unroll
            for (int j = 0; j < NR; ++j)
                acc[i][j] = __builtin_amdgcn_mfma_f32_16x16x32_bf16(af[i], bf[j], acc[i][j], 0, 0, 0);
        __builtin_amdgcn_s_setprio(0);
    };

    // prologue: tile 0 into buf 0
    stgA(0, 0); stgB(0, 0);

    for (int ii = 0; ii < 8; ++ii) {
        const int t1 = 2 * ii + 1;
        const int t2 = (ii < 7) ? 2 * ii + 2 : 15;   // tail clamp (dead restage)
        // tile even (buf 0)
        stgA(1, t1); VM2(); BARX();
        lda(0, 0); ldb(0, 0); mm();
        stgB(1, t1);
        lda(0, 1); ldb(0, 1); mm();
        BARX();
        // tile odd (buf 1)
        stgA(0, t2); VM2(); BARX();
        lda(1, 0); ldb(1, 0); mm();
        stgB(0, t2);
        lda(1, 1); ldb(1, 1); mm();
        BARX();
    }
}

// ---- QKV: C = xb @ qkv_w^T (+bias), scatter into Q/K/V [B*H, T, D] bf16 ----
// Tile 128x192 (NR=3), 80KB LDS -> 2 blocks/CU; grid 1024 = 2 rounds of 512.
__global__ __launch_bounds__(512, 4) void gemm_qkv(
    const u16* __restrict__ Amat, const u16* __restrict__ Bw,
    const float* __restrict__ bias,
    u16* __restrict__ Qb, u16* __restrict__ Kb, u16* __restrict__ Vb)
{
    __shared__ u16 lA[2 * 8192];    // 32 KB
    __shared__ u16 lB[2 * 12288];   // 48 KB
    // XCD x owns m-tiles 8x..8x+7 (A slice 1MB, L2-resident), all 16 n-tiles.
    const int raw = blockIdx.x;
    const int xcd = raw & 7;
    const int l   = raw >> 3;               // 0..127
    const int bM  = (xcd * 8 + (l & 7)) * 128;
    const int bN  = (l >> 3) * 192;         // n-tile 0..15

    floatx4 acc[4][3] = {};
    gemm_core<3>(Amat, Bw, bM, bN, lA, lB, acc);

    const int tid = threadIdx.x;
    const int wave = tid >> 6, lane = tid & 63;
    const int wm = wave >> 2, wn = wave & 3;
    const int quad = lane >> 4, l15 = lane & 15;

    // epilogue: +bias, bf16, QKV scatter
#pragma unroll
    for (int mf = 0; mf < 4; ++mf)
#pragma unroll
        for (int nf = 0; nf < 3; ++nf) {
            int col = bN + wn * 48 + nf * 16 + l15;          // 0..3071
            float bv = bias[col];
            int which = col >> 10, rem = col & 1023;
            int h = rem >> 6, d = rem & 63;
            u16* dst = which == 0 ? Qb : (which == 1 ? Kb : Vb);
#pragma unroll
            for (int rg = 0; rg < 4; ++rg) {
                int row = bM + wm * 64 + mf * 16 + quad * 4 + rg;  // 0..8191
                int b = row >> 11, t = row & 2047;
                float v = acc[mf][nf][rg] + bv;
                dst[(((size_t)(b * HH + h)) * TT + t) * DD + d] = f2bf(v);
            }
        }
}

// ---- proj: Out = Yb @ proj_w^T + bias (fp32 out) ----
// Tile 128x128 (NR=2), 64KB LDS -> 2 blocks/CU; grid 512 = 1 round of 512.
__global__ __launch_bounds__(512, 4) void gemm_proj(
    const u16* __restrict__ Amat, const u16* __restrict__ Bw,
    const float* __restrict__ bias, float* __restrict__ Out)
{
    __shared__ u16 lA[2 * 8192];    // 32 KB
    __shared__ u16 lB[2 * 8192];    // 32 KB
    const int raw = blockIdx.x;
    const int xcd = raw & 7;
    const int l   = raw >> 3;               // 0..63
    const int bM  = (xcd * 8 + (l & 7)) * 128;
    const int bN  = (l >> 3) * 128;         // n-tile 0..7

    floatx4 acc[4][2] = {};
    gemm_core<2>(Amat, Bw, bM, bN, lA, lB, acc);

    const int tid = threadIdx.x;
    const int wave = tid >> 6, lane = tid & 63;
    const int wm = wave >> 2, wn = wave & 3;
    const int quad = lane >> 4, l15 = lane & 15;

    // epilogue: +bias, fp32 out
#pragma unroll
    for (int mf = 0; mf < 4; ++mf)
#pragma unroll
        for (int nf = 0; nf < 2; ++nf) {
            int col = bN + wn * 32 + nf * 16 + l15;
            float bv = bias[col];
#pragma unroll
            for (int rg = 0; rg < 4; ++rg) {
                int row = bM + wm * 64 + mf * 16 + quad * 4 + rg;
                Out[(size_t)row * CC + col] = acc[mf][nf][rg] + bv;
            }
        }
}

// ---------------- flash attention, MFMA (bf16 in, fp32 acc) ------------------
// Q/K/V: [B*H, T, D] bf16.  Y: [B, T, C] bf16 (transposed for proj GEMM)
// Block: 256 threads = 4 waves; 64 queries/block (16/wave); key chunks of 64.
// Grid (bh, qtile): linear id = bh + 64*qtile -> all q-tiles of a head hit the
// SAME XCD (id%8 = bh%8) -> K/V chunks L2-resident across their ~5 consumer
// q-tiles. setprio(1) around MFMA clusters (measured-positive attn regime).
__global__ __launch_bounds__(256) void attn_mfma(
    const u16* __restrict__ Qb, const u16* __restrict__ Kb, const u16* __restrict__ Vb,
    u16* __restrict__ Y)
{
    __shared__ u16 Ks[64][72];        // K chunk, [j][d], +8 pad
    __shared__ u16 Vt[64][72];        // V chunk transposed [d][j], XOR-swizzled j-blocks
    __shared__ u16 Ps[4][16][72];     // per-wave P round-trip buffer [q][j]

    const int tid = threadIdx.x;
    const int wave = tid >> 6, lane = tid & 63;
    const int quad = lane >> 4, l15 = lane & 15;
    const int q0 = blockIdx.y * 64;
    const int bh = blockIdx.x;
    const int b = bh >> 4, h = bh & 15;
    const u16* Qp = Qb + (size_t)bh * TT * DD;
    const u16* Kp = Kb + (size_t)bh * TT * DD;
    const u16* Vp = Vb + (size_t)bh * TT * DD;
    const int qw = q0 + wave * 16;    // this wave's first query

    // Q A-fragments: m=l15 (query), k=quad*8+j (d), 2 k-steps
    short8 qf[2];
    qf[0] = *(const short8*)&Qp[(size_t)(qw + l15) * DD + quad * 8];
    qf[1] = *(const short8*)&Qp[(size_t)(qw + l15) * DD + 32 + quad * 8];

    float m_i[4] = { -1e30f, -1e30f, -1e30f, -1e30f };
    float l_i[4] = { 0.f, 0.f, 0.f, 0.f };
    floatx4 Oacc[4] = {};             // [dtile]; C layout: row=quad*4+reg, col(d)=dt*16+l15

    const int kb = (q0 >= WIN) ? (q0 - WIN) : 0;
    for (int j0 = kb; j0 < q0 + 64; j0 += 64) {
        __syncthreads();
        // stage K chunk [j][d], vectorized
#pragma unroll
        for (int it = 0; it < 2; ++it) {
            int slot = tid + it * 256;
            int j = slot >> 3, c8 = (slot & 7) << 3;
            *(uint4*)&Ks[j][c8] = *(const uint4*)&Kp[(size_t)(j0 + j) * DD + c8];
        }
        // stage V transposed [d][j], swizzle j-block by d>>3 (conflict-free writes)
#pragma unroll
        for (int it = 0; it < 2; ++it) {
            int slot = tid + it * 256;
            int j = slot >> 3, d0 = (slot & 7) << 3;
            uint4 raw = *(const uint4*)&Vp[(size_t)(j0 + j) * DD + d0];
            const u16* u = (const u16*)&raw;
#pragma unroll
            for (int i = 0; i < 8; ++i) {
                int d = d0 + i;
                int col = (((j >> 3) ^ (d >> 3)) << 3) + (j & 7);
                Vt[d][col] = u[i];
            }
        }
        __syncthreads();

        // ---- S = Q K^T (scaled), 4 n-tiles of 16 keys ----
        floatx4 Sacc[4] = {};
        __builtin_amdgcn_s_setprio(1);
#pragma unroll
        for (int nt = 0; nt < 4; ++nt) {
            short8 kf0 = *(const short8*)&Ks[nt * 16 + l15][quad * 8];
            short8 kf1 = *(const short8*)&Ks[nt * 16 + l15][32 + quad * 8];
            Sacc[nt] = __builtin_amdgcn_mfma_f32_16x16x32_bf16(qf[0], kf0, Sacc[nt], 0, 0, 0);
            Sacc[nt] = __builtin_amdgcn_mfma_f32_16x16x32_bf16(qf[1], kf1, Sacc[nt], 0, 0, 0);
        }
        __builtin_amdgcn_s_setprio(0);

        // ---- mask + scale + chunk row-max ----
        float mc[4] = { -1e30f, -1e30f, -1e30f, -1e30f };
#pragma unroll
        for (int nt = 0; nt < 4; ++nt)
#pragma unroll
            for (int r = 0; r < 4; ++r) {
                int q = qw + quad * 4 + r;
                int j = j0 + nt * 16 + l15;
                float s = (j <= q && (q - j) < WIN) ? Sacc[nt][r] * 0.125f : -1e30f;
                Sacc[nt][r] = s;
                mc[r] = fmaxf(mc[r], s);
            }
#pragma unroll
        for (int m = 1; m < 16; m <<= 1)
#pragma unroll
            for (int r = 0; r < 4; ++r) mc[r] = fmaxf(mc[r], __shfl_xor(mc[r], m, 64));

        // ---- online softmax update ----
        float alpha[4];
#pragma unroll
        for (int r = 0; r < 4; ++r) {
            float mn = fmaxf(m_i[r], mc[r]);
            alpha[r] = __expf(m_i[r] - mn);
            m_i[r] = mn;
        }
        float rs[4] = { 0.f, 0.f, 0.f, 0.f };
#pragma unroll
        for (int nt = 0; nt < 4; ++nt)
#pragma unroll
            for (int r = 0; r < 4; ++r) {
                float s = Sacc[nt][r];
                float p = (s > -1e29f) ? __expf(s - m_i[r]) : 0.f;
                Sacc[nt][r] = p;
                rs[r] += p;
            }
#pragma unroll
        for (int m = 1; m < 16; m <<= 1)
#pragma unroll
            for (int r = 0; r < 4; ++r) rs[r] += __shfl_xor(rs[r], m, 64);
#pragma unroll
        for (int r = 0; r < 4; ++r) l_i[r] = l_i[r] * alpha[r] + rs[r];
#pragma unroll
        for (int dt = 0; dt < 4; ++dt)
#pragma unroll
            for (int r = 0; r < 4; ++r) Oacc[dt][r] *= alpha[r];

        // ---- P (C layout) -> LDS -> A layout; per-wave, no barrier needed ----
#pragma unroll
        for (int nt = 0; nt < 4; ++nt)
#pragma unroll
            for (int r = 0; r < 4; ++r)
                Ps[wave][quad * 4 + r][nt * 16 + l15] = f2bf(Sacc[nt][r]);

        // ---- O += P V ----
        __builtin_amdgcn_s_setprio(1);
#pragma unroll
        for (int ks = 0; ks < 2; ++ks) {
            short8 pf = *(const short8*)&Ps[wave][l15][ks * 32 + quad * 8];
#pragma unroll
            for (int dt = 0; dt < 4; ++dt) {
                int d = dt * 16 + l15;
                int col = (((ks * 4 + quad) ^ (d >> 3)) << 3);
                short8 vf = *(const short8*)&Vt[d][col];
                Oacc[dt] = __builtin_amdgcn_mfma_f32_16x16x32_bf16(pf, vf, Oacc[dt], 0, 0, 0);
            }
        }
        __builtin_amdgcn_s_setprio(0);
    }

    // ---- epilogue: O / l, write Y[b,t,h*64+d] ----
    float inv[4];
#pragma unroll
    for (int r = 0; r < 4; ++r) inv[r] = 1.f / l_i[r];
#pragma unroll
    for (int dt = 0; dt < 4; ++dt)
#pragma unroll
        for (int r = 0; r < 4; ++r) {
            int t = qw + quad * 4 + r;
            int d = dt * 16 + l15;
            Y[((size_t)b * TT + t) * CC + h * DD + d] = f2bf(Oacc[dt][r] * inv[r]);
        }
}

// ---------------- launch ----------------
extern "C" void kernel_launch(void* const* d_in, const int* in_sizes, int n_in,
                              void* d_out, int out_size, void* d_ws, size_t ws_size,
                              hipStream_t stream) {
    const float* x      = (const float*)d_in[0];
    // d_in[1] = attn_mask (bool) — mask structure is analytic, unused
    const float* qkv_w  = (const float*)d_in[2];
    const float* qkv_b  = (const float*)d_in[3];
    const float* proj_w = (const float*)d_in[4];
    const float* proj_b = (const float*)d_in[5];
    float* out = (float*)d_out;

    u16* xb  = (u16*)d_ws;                         // 8192*1024
    u16* wb  = xb  + (size_t)8192 * 1024;          // 3072*1024
    u16* pwb = wb  + (size_t)3072 * 1024;          // 1024*1024
    u16* Qb  = pwb + (size_t)1024 * 1024;          // 64*2048*64
    u16* Kb  = Qb  + (size_t)64 * 2048 * 64;
    u16* Vb  = Kb  + (size_t)64 * 2048 * 64;
    u16* Yb  = Vb  + (size_t)64 * 2048 * 64;       // 8192*1024

    cvt_all<<<6144, 256, 0, stream>>>(x, qkv_w, proj_w, xb, wb, pwb);
    gemm_qkv<<<1024, 512, 0, stream>>>(xb, wb, qkv_b, Qb, Kb, Vb);
    attn_mfma<<<dim3(BB * HH, TT / 64), 256, 0, stream>>>(Qb, Kb, Vb, Yb);
    gemm_proj<<<512, 512, 0, stream>>>(Yb, pwb, proj_b, out);
}